// Round 1
// baseline (187.887 us; speedup 1.0000x reference)
//
#include <hip/hip_runtime.h>

#define NORM_EPS 1e-12f

// Kernel 1: per-row inverse L2 norm. One 64-lane wave per row, float2/lane.
__global__ void inv_norm_kernel(const float* __restrict__ emb,
                                float* __restrict__ inv_norm,
                                int n_nodes) {
    int gtid   = blockIdx.x * blockDim.x + threadIdx.x;
    int wave   = gtid >> 6;
    int lane   = threadIdx.x & 63;
    int n_wave = (gridDim.x * blockDim.x) >> 6;

    for (int row = wave; row < n_nodes; row += n_wave) {
        const float2* p = (const float2*)(emb + (size_t)row * 128);
        float2 v = p[lane];                       // 64 lanes x 8B = 512B row
        float s = v.x * v.x + v.y * v.y;
        #pragma unroll
        for (int off = 32; off > 0; off >>= 1)
            s += __shfl_down(s, off);
        if (lane == 0)
            inv_norm[row] = 1.0f / fmaxf(sqrtf(s), NORM_EPS);
    }
}

// Kernel 2: one half-wave (32 lanes) per edge; float4/lane gathers of the
// src and dst rows (512B each, row-aligned), weighted dot, shuffle reduce.
__global__ void edge_dot_kernel(const float* __restrict__ emb,
                                const int* __restrict__ esrc,
                                const int* __restrict__ edst,
                                const float* __restrict__ dvec,
                                const float* __restrict__ scale,
                                const float* __restrict__ inv_norm,
                                float* __restrict__ out,
                                int n_edges) {
    int gtid   = blockIdx.x * blockDim.x + threadIdx.x;
    int half   = gtid >> 5;                 // half-wave id == edge id
    int lane   = threadIdx.x & 31;
    int n_half = (gridDim.x * blockDim.x) >> 5;
    float sc = scale[0];

    for (int e = half; e < n_edges; e += n_half) {
        int si = esrc[e];
        int di = edst[e];
        const float4* ps = (const float4*)(emb + (size_t)si * 128);
        const float4* pd = (const float4*)(emb + (size_t)di * 128);
        const float4* pw = (const float4*)dvec;
        float4 a = ps[lane];                // 32 lanes x 16B = 512B
        float4 b = pd[lane];
        float4 w = pw[lane];                // L1-resident after first touch
        float dot = a.x * b.x * w.x
                  + a.y * b.y * w.y
                  + a.z * b.z * w.z
                  + a.w * b.w * w.w;
        #pragma unroll
        for (int off = 16; off > 0; off >>= 1)
            dot += __shfl_down(dot, off, 32);
        if (lane == 0)
            out[e] = dot * inv_norm[si] * inv_norm[di] * sc;
    }
}

extern "C" void kernel_launch(void* const* d_in, const int* in_sizes, int n_in,
                              void* d_out, int out_size, void* d_ws, size_t ws_size,
                              hipStream_t stream) {
    const float* emb   = (const float*)d_in[0];
    const int*   esrc  = (const int*)d_in[1];
    const int*   edst  = (const int*)d_in[2];
    const float* dvec  = (const float*)d_in[3];
    const float* scale = (const float*)d_in[4];
    float*       out   = (float*)d_out;

    int n_nodes = in_sizes[0] / 128;
    int n_edges = in_sizes[1];

    float* inv_norm = (float*)d_ws;         // n_nodes floats of scratch

    {   // 4 rows per 256-thread block
        int blocks = (n_nodes + 3) / 4;
        inv_norm_kernel<<<blocks, 256, 0, stream>>>(emb, inv_norm, n_nodes);
    }
    {   // 8 edges per 256-thread block
        int blocks = (n_edges + 7) / 8;
        edge_dot_kernel<<<blocks, 256, 0, stream>>>(emb, esrc, edst, dvec,
                                                    scale, inv_norm, out, n_edges);
    }
}

// Round 2
// 137.533 us; speedup vs baseline: 1.3661x; 1.3661x over previous
//
#include <hip/hip_runtime.h>

#define NORM_EPS 1e-12f

__device__ __forceinline__ float bf16_lo_to_f(unsigned u) {
    union { unsigned u; float f; } c; c.u = u << 16; return c.f;
}
__device__ __forceinline__ float bf16_hi_to_f(unsigned u) {
    union { unsigned u; float f; } c; c.u = u & 0xFFFF0000u; return c.f;
}
__device__ __forceinline__ unsigned f_to_bf16_rne(float f) {
    union { float f; unsigned u; } c; c.f = f;
    return (c.u + 0x7FFFu + ((c.u >> 16) & 1u)) >> 16;
}

// Kernel 1: L2-normalize each row, emit bf16 table (norms folded in).
// One 64-lane wave per row; float2/lane in, packed 2xbf16 dword/lane out.
__global__ void norm_bf16_kernel(const float* __restrict__ emb,
                                 unsigned* __restrict__ tbl,   // n_nodes*64 dwords
                                 int n_nodes) {
    int wave = (blockIdx.x * blockDim.x + threadIdx.x) >> 6;
    int lane = threadIdx.x & 63;
    if (wave >= n_nodes) return;
    const float2* p = (const float2*)(emb + (size_t)wave * 128);
    float2 v = p[lane];
    float s = v.x * v.x + v.y * v.y;
    #pragma unroll
    for (int off = 32; off > 0; off >>= 1)
        s += __shfl_xor(s, off);                  // butterfly: all lanes get sum
    float inv = 1.0f / fmaxf(sqrtf(s), NORM_EPS);
    unsigned lo = f_to_bf16_rne(v.x * inv);
    unsigned hi = f_to_bf16_rne(v.y * inv);
    tbl[(size_t)wave * 64 + lane] = lo | (hi << 16);
}

__device__ __forceinline__ float dot8(uint4 a, uint4 b, float4 w0, float4 w1) {
    float s;
    s  = bf16_lo_to_f(a.x) * bf16_lo_to_f(b.x) * w0.x;
    s += bf16_hi_to_f(a.x) * bf16_hi_to_f(b.x) * w0.y;
    s += bf16_lo_to_f(a.y) * bf16_lo_to_f(b.y) * w0.z;
    s += bf16_hi_to_f(a.y) * bf16_hi_to_f(b.y) * w0.w;
    s += bf16_lo_to_f(a.z) * bf16_lo_to_f(b.z) * w1.x;
    s += bf16_hi_to_f(a.z) * bf16_hi_to_f(b.z) * w1.y;
    s += bf16_lo_to_f(a.w) * bf16_lo_to_f(b.w) * w1.z;
    s += bf16_hi_to_f(a.w) * bf16_hi_to_f(b.w) * w1.w;
    return s;
}

// Kernel 2: 16 lanes per edge, 2 edges per lane-group (4 row-gathers in
// flight per group). Row = 256 B bf16 = 16 lanes x uint4. d in registers.
__global__ void edge_dot_bf16_kernel(const uint4* __restrict__ tbl,
                                     const int* __restrict__ esrc,
                                     const int* __restrict__ edst,
                                     const float* __restrict__ dvec,
                                     const float* __restrict__ scale,
                                     float* __restrict__ out,
                                     int n_edges) {
    int g    = (blockIdx.x * blockDim.x + threadIdx.x) >> 4;   // pair id
    int lane = threadIdx.x & 15;
    int e0 = g * 2, e1 = e0 + 1;
    if (e0 >= n_edges) return;
    bool has1 = e1 < n_edges;

    int s0 = esrc[e0], t0 = edst[e0];
    int s1 = has1 ? esrc[e1] : s0;
    int t1 = has1 ? edst[e1] : t0;

    uint4 a0 = tbl[(size_t)s0 * 16 + lane];   // 4 independent 256B gathers
    uint4 b0 = tbl[(size_t)t0 * 16 + lane];
    uint4 a1 = tbl[(size_t)s1 * 16 + lane];
    uint4 b1 = tbl[(size_t)t1 * 16 + lane];

    const float4* dv = (const float4*)dvec;
    float4 w0 = dv[lane * 2];
    float4 w1 = dv[lane * 2 + 1];

    float acc0 = dot8(a0, b0, w0, w1);
    float acc1 = dot8(a1, b1, w0, w1);

    #pragma unroll
    for (int off = 8; off > 0; off >>= 1) {
        acc0 += __shfl_xor(acc0, off);
        acc1 += __shfl_xor(acc1, off);
    }

    if (lane == 0) {
        float sc = scale[0];
        out[e0] = acc0 * sc;
        if (has1) out[e1] = acc1 * sc;
    }
}

extern "C" void kernel_launch(void* const* d_in, const int* in_sizes, int n_in,
                              void* d_out, int out_size, void* d_ws, size_t ws_size,
                              hipStream_t stream) {
    const float* emb   = (const float*)d_in[0];
    const int*   esrc  = (const int*)d_in[1];
    const int*   edst  = (const int*)d_in[2];
    const float* dvec  = (const float*)d_in[3];
    const float* scale = (const float*)d_in[4];
    float*       out   = (float*)d_out;

    int n_nodes = in_sizes[0] / 128;
    int n_edges = in_sizes[1];

    unsigned* tbl = (unsigned*)d_ws;   // n_nodes * 256 B bf16 table (25.6 MB)

    {   // 4 rows per 256-thread block
        int blocks = (n_nodes + 3) / 4;
        norm_bf16_kernel<<<blocks, 256, 0, stream>>>(emb, tbl, n_nodes);
    }
    {
        int n_pairs = (n_edges + 1) / 2;
        long long threads = (long long)n_pairs * 16;
        int blocks = (int)((threads + 255) / 256);
        edge_dot_bf16_kernel<<<blocks, 256, 0, stream>>>(
            (const uint4*)tbl, esrc, edst, dvec, scale, out, n_edges);
    }
}